// Round 8
// baseline (14618.842 us; speedup 1.0000x reference)
//
#include <hip/hip_runtime.h>
#include <cfloat>
#include <cmath>

#define Bn 128
#define Tn 512
#define En 256
#define Hn 512
#define NTAGS 32

// ws float offsets (h stored [k][b] dense)
#define OFF_HF 0                          // [2][512][128]
#define OFF_HB 131072
#define OFF_CF 262144                     // [512][128]
#define OFF_CB 327680
#define OFF_EF 393216                     // [512][32][128]
#define OFF_EB 2490368
// end 4587520 floats = 17.5 MB

__device__ __forceinline__ void gll16(const float* g, float* l) {
  __builtin_amdgcn_global_load_lds(
      (const __attribute__((address_space(1))) void*)g,
      (__attribute__((address_space(3))) void*)l, 16, 0, 0);
}

__device__ __forceinline__ void wait_vm4() {
  asm volatile("s_waitcnt vmcnt(4)" ::: "memory");
  __builtin_amdgcn_sched_barrier(0);
}
__device__ __forceinline__ void wait_vm0() {
  asm volatile("s_waitcnt vmcnt(0)" ::: "memory");
  __builtin_amdgcn_sched_barrier(0);
}
__device__ __forceinline__ void wait_lgkm0() {
  asm volatile("s_waitcnt lgkmcnt(0)" ::: "memory");
  __builtin_amdgcn_sched_barrier(0);
}
__device__ __forceinline__ void barrier_raw() {
  __builtin_amdgcn_sched_barrier(0);
  __builtin_amdgcn_s_barrier();
  __builtin_amdgcn_sched_barrier(0);
}

__global__ __launch_bounds__(512, 2) void lstm_step_k(
    const float* __restrict__ X, const float* __restrict__ masks,
    const float* __restrict__ Wih_f, const float* __restrict__ Whh_f, const float* __restrict__ bias_f,
    const float* __restrict__ Wih_b, const float* __restrict__ Whh_b, const float* __restrict__ bias_b,
    const float* __restrict__ Wout, float* __restrict__ ws, int s)
{
  __shared__ __align__(16) float WT[768 * 16];     // 48 KB  W [k][c]
  __shared__ __align__(16) float HXf[3 * 64 * 128];// 96 KB  3 A-buffers [k][b] dense
  __shared__ __align__(16) float GL[128 * 17];     // 8.5 KB gates
  __shared__ __align__(16) float WoL[512];         // 2 KB   Wout row
  __shared__ __align__(16) float RS[8 * 128];      // 4 KB   emission partials

  const int tid  = threadIdx.x;
  const int blk  = blockIdx.x;
  const int lane = tid & 63;
  const int wid  = __builtin_amdgcn_readfirstlane(tid >> 6);  // 0..7 uniform
  const int kq   = wid;         // k-octile of each chunk: [kq*8, +8)
  const int bg   = lane & 31;   // b quad: [bg*4, +4)
  const int kh   = lane >> 5;   // k parity within pair

  const int dir = blk >> 7;
  const int bbk = blk & 127;
  const int t = dir ? (Tn - 1 - s) : s;
  const float* Wih  = dir ? Wih_b  : Wih_f;
  const float* Whh  = dir ? Whh_b  : Whh_f;
  const float* bias = dir ? bias_b : bias_f;
  float* hbuf = ws + (dir ? OFF_HB : OFF_HF);
  float* cbuf = ws + (dir ? OFF_CB : OFF_CF);
  const int rbuf = (s + 1) & 1;
  const int wbuf = s & 1;
  const float* hprev = hbuf + rbuf * (Hn * Bn);
  float*       hnext = hbuf + wbuf * (Hn * Bn);
  const int hidx0 = bbk * 4;
  const int etag = bbk & 31;
  const int ebq  = bbk >> 5;

  // ---- earliest loads: epilogue data (drains before pipeline counting) ----
  const int pb  = tid & 127;
  const int phh = tid >> 7;
  const int hidxp = hidx0 + phh;
  const float mval = masks[(size_t)pb * Tn + t];
  const float bi  = bias[hidxp];
  const float bf_ = bias[Hn + hidxp];
  const float bg_ = bias[2 * Hn + hidxp];
  const float bo_ = bias[3 * Hn + hidxp];
  const float cold = cbuf[hidxp * Bn + pb];
  const float hold = hprev[hidxp * Bn + pb];
  float wol_v = 0.f;
  if (tid < 128) {
    const float4 wo = *(const float4*)&Wout[(size_t)etag * (2 * Hn) + dir * Hn + tid * 4];
    *(float4*)&WoL[tid * 4] = wo;   // LDS write; drained by prologue lgkmcnt(0)
    wol_v = wo.x;                    // keep value live
  }
  (void)wol_v;

  // ---- prologue: issue gll16 for chunks 0 and 1, then stage W ----
  #pragma unroll
  for (int r = 0; r < 4; ++r) {
    const int item = r * 512 + tid;
    gll16(hprev + item * 4, &HXf[0 * 8192 + item * 4]);
  }
  #pragma unroll
  for (int r = 0; r < 4; ++r) {
    const int item = r * 512 + tid;
    gll16(hprev + 8192 + item * 4, &HXf[1 * 8192 + item * 4]);
  }
  {
    const int lc = tid & 15;
    const int kw = tid >> 4;                       // 0..31
    const int row = (lc >> 2) * Hn + hidx0 + (lc & 3);
    #pragma unroll
    for (int i = 0; i < 6; ++i) {
      const int k = (kw + i * 32) * 4;             // 0..764
      float4 w4;
      if (k < Hn) w4 = *(const float4*)&Whh[(size_t)row * Hn + k];
      else        w4 = *(const float4*)&Wih[(size_t)row * En + (k - Hn)];
      WT[(k + 0) * 16 + lc] = w4.x; WT[(k + 1) * 16 + lc] = w4.y;
      WT[(k + 2) * 16 + lc] = w4.z; WT[(k + 3) * 16 + lc] = w4.w;
    }
  }
  asm volatile("s_waitcnt vmcnt(4) lgkmcnt(0)" ::: "memory");  // chunk0 + W/WoL done
  __builtin_amdgcn_sched_barrier(0);
  barrier_raw();

  float acc[4][16];
  #pragma unroll
  for (int m = 0; m < 4; ++m)
    #pragma unroll
    for (int n = 0; n < 16; ++n) acc[m][n] = 0.f;
  float eac[4] = {0.f, 0.f, 0.f, 0.f};

  const int xbq = tid & 127;
  const int xeg = tid >> 7;
  float4 xA[4], xB[4];

#define STORE_X(REGS, CW)                                              \
  {                                                                    \
    float* dst_ = &HXf[((CW) % 3) * 8192];                             \
    _Pragma("unroll")                                                  \
    for (int r = 0; r < 4; ++r) {                                      \
      const int el = xeg * 16 + r * 4;                                 \
      dst_[(el + 0) * 128 + xbq] = REGS[r].x;                          \
      dst_[(el + 1) * 128 + xbq] = REGS[r].y;                          \
      dst_[(el + 2) * 128 + xbq] = REGS[r].z;                          \
      dst_[(el + 3) * 128 + xbq] = REGS[r].w;                          \
    }                                                                  \
  }

  // ---- main loop: 12 chunks (0..7 h, 8..11 x), depth-2 prefetch ----
  #pragma unroll 1
  for (int c = 0; c < 12; ++c) {
    // (1) prefetch chunk c+2
    if (c + 2 <= 7) {
      const float* src = hprev + (c + 2) * 8192;
      float* dst = &HXf[((c + 2) % 3) * 8192];
      #pragma unroll
      for (int r = 0; r < 4; ++r) {
        const int item = r * 512 + tid;
        gll16(src + item * 4, dst + item * 4);
      }
    } else if (c + 2 <= 11) {
      const int e0 = (c + 2 - 8) * 64;
      const float* xsrc = &X[(size_t)xbq * (Tn * En) + (size_t)t * En + e0 + xeg * 16];
      if (((c + 2) & 1) == 0) {
        #pragma unroll
        for (int r = 0; r < 4; ++r) xA[r] = *(const float4*)(xsrc + r * 4);
      } else {
        #pragma unroll
        for (int r = 0; r < 4; ++r) xB[r] = *(const float4*)(xsrc + r * 4);
      }
    }

    // (2) compute chunk c
    {
      const float* HXc = &HXf[(c % 3) * 8192];
      const int kw0 = c * 64;
      #pragma unroll
      for (int j = 0; j < 4; ++j) {
        const int kl = kq * 8 + j * 2 + kh;
        const float4 av = *(const float4*)&HXc[kl * 128 + bg * 4];
        const float4 w0 = *(const float4*)&WT[(kw0 + kl) * 16];
        const float4 w1 = *(const float4*)&WT[(kw0 + kl) * 16 + 4];
        const float4 w2 = *(const float4*)&WT[(kw0 + kl) * 16 + 8];
        const float4 w3 = *(const float4*)&WT[(kw0 + kl) * 16 + 12];
        const float a_[4]  = {av.x, av.y, av.z, av.w};
        const float w_[16] = {w0.x, w0.y, w0.z, w0.w, w1.x, w1.y, w1.z, w1.w,
                              w2.x, w2.y, w2.z, w2.w, w3.x, w3.y, w3.z, w3.w};
        #pragma unroll
        for (int m = 0; m < 4; ++m)
          #pragma unroll
          for (int n = 0; n < 16; ++n)
            acc[m][n] += a_[m] * w_[n];
        if (c < 8) {
          const float wo = WoL[kw0 + kl];
          eac[0] += a_[0] * wo; eac[1] += a_[1] * wo;
          eac[2] += a_[2] * wo; eac[3] += a_[3] * wo;
        }
      }
    }

    // (3) sync: counted vmcnt; x ds_writes for chunk c+1
    if (c < 11) {
      if (c <= 6) {
        wait_vm4();                      // gll16(c+1) complete (c==6: x8 stays in flight)
      } else if (c <= 9) {
        wait_vm4();                      // x(c+1) regs arrived, x(c+2) in flight
        if (((c + 1) & 1) == 0) { STORE_X(xA, c + 1) } else { STORE_X(xB, c + 1) }
        wait_lgkm0();
      } else {                           // c == 10
        wait_vm0();                      // x11 regs arrived (nothing else in flight)
        STORE_X(xB, 11)
        wait_lgkm0();
      }
      barrier_raw();
    }
  }
#undef STORE_X

  // ---- kh reduce in-register, then k-split (8) reduction via LDS ----
  #pragma unroll
  for (int m = 0; m < 4; ++m)
    #pragma unroll
    for (int n = 0; n < 16; ++n)
      acc[m][n] += __shfl_xor(acc[m][n], 32);
  #pragma unroll
  for (int m = 0; m < 4; ++m) eac[m] += __shfl_xor(eac[m], 32);

  float* P = &HXf[0];                              // overlay bufs 0,1 (64 KB); buf2 unused now
  if (kh == 0) {
    #pragma unroll
    for (int n = 0; n < 16; ++n)
      *(float4*)&P[kq * 2048 + n * 128 + bg * 4] =
          make_float4(acc[0][n], acc[1][n], acc[2][n], acc[3][n]);
    *(float4*)&RS[kq * 128 + bg * 4] = make_float4(eac[0], eac[1], eac[2], eac[3]);
  }
  __syncthreads();
  {
    const int b  = tid & 127;
    const int cq = tid >> 7;
    float g4[4] = {0.f, 0.f, 0.f, 0.f};
    #pragma unroll
    for (int k2 = 0; k2 < 8; ++k2)
      #pragma unroll
      for (int ci = 0; ci < 4; ++ci)
        g4[ci] += P[k2 * 2048 + (cq * 4 + ci) * 128 + b];
    #pragma unroll
    for (int ci = 0; ci < 4; ++ci)
      GL[b * 17 + cq * 4 + ci] = g4[ci];
  }
  __syncthreads();

  // ---- LSTM pointwise update (inputs preloaded) ----
  {
    const float gi = GL[pb * 17 + phh]       + bi;
    const float gf = GL[pb * 17 + 4 + phh]   + bf_;
    const float gc = GL[pb * 17 + 8 + phh]   + bg_;
    const float go = GL[pb * 17 + 12 + phh]  + bo_;
    const float iv = 1.f / (1.f + expf(-gi));
    const float fv = 1.f / (1.f + expf(-gf));
    const float gv = tanhf(gc);
    const float ov = 1.f / (1.f + expf(-go));
    const float cnew = fv * cold + iv * gv;
    const float hnew = ov * tanhf(cnew);
    hnext[hidxp * Bn + pb] = (mval > 0.f) ? hnew : hold;
    cbuf[hidxp * Bn + pb]  = (mval > 0.f) ? cnew : cold;
  }

  // ---- emission finish: full 128-b row, written by ebq==0 blocks only ----
  if (s > 0 && ebq == 0 && tid < 128) {
    const int tprev = dir ? (Tn - s) : (s - 1);
    float* Edst = ws + (dir ? OFF_EB : OFF_EF);
    float v = 0.f;
    #pragma unroll
    for (int g = 0; g < 8; ++g) v += RS[g * 128 + tid];
    Edst[(size_t)tprev * (NTAGS * Bn) + etag * Bn + tid] = v;
  }
}

__global__ __launch_bounds__(512) void emis_final_k(const float* __restrict__ Wout,
                                                    float* __restrict__ ws)
{
  __shared__ float RSf[16 * Bn];
  const int tid = threadIdx.x;
  const int dir = blockIdx.x >> 5;
  const int tag = blockIdx.x & 31;
  // final states: h_f[T-1] and h_b[0] both written at s=511 (wbuf=1)
  const float* hsrc = ws + (dir ? OFF_HB : OFF_HF) + 1 * (Hn * Bn);
  const int tprev = dir ? 0 : (Tn - 1);
  const float* wrow = Wout + (size_t)tag * (2 * Hn) + dir * Hn;
  float* Edst = ws + (dir ? OFF_EB : OFF_EF);
  const int bq = tid & 31;
  const int kg = tid >> 5;
  float4 a4 = make_float4(0.f, 0.f, 0.f, 0.f);
  #pragma unroll 4
  for (int kk = 0; kk < 32; ++kk) {
    const int k = kg * 32 + kk;
    const float w = wrow[k];
    const float4 h4 = *(const float4*)&hsrc[k * Bn + bq * 4];
    a4.x += h4.x * w; a4.y += h4.y * w; a4.z += h4.z * w; a4.w += h4.w * w;
  }
  *(float4*)&RSf[kg * Bn + bq * 4] = a4;
  __syncthreads();
  if (tid < 128) {
    float v = 0.f;
    #pragma unroll
    for (int g = 0; g < 16; ++g) v += RSf[g * Bn + tid];
    Edst[(size_t)tprev * (NTAGS * Bn) + tag * Bn + tid] = v;
  }
}

__global__ __launch_bounds__(64) void viterbi_k(
    const float* __restrict__ Ef, const float* __restrict__ Eb,
    const float* __restrict__ bout, const float* __restrict__ trans,
    const float* __restrict__ masks, float* __restrict__ out)
{
  const int b = blockIdx.x;
  const int l = threadIdx.x;
  __shared__ float tr[32][32];
  __shared__ float al[32];
  __shared__ float msk[512];
  __shared__ unsigned char bp[512][32];
  __shared__ int tseq[512];

  for (int i = l; i < 1024; i += 64) tr[i >> 5][i & 31] = trans[i];
  for (int i = l; i < 512; i += 64) msk[i] = masks[(size_t)b * 512 + i];
  __syncthreads();

  const int j  = l & 31;
  const int hi = l >> 5;
  if (l < 32)
    al[j] = Ef[(size_t)j * Bn + b] + Eb[(size_t)j * Bn + b] + bout[j] + tr[30][j];
  __syncthreads();

  for (int t = 1; t < 512; ++t) {
    float pmax = -FLT_MAX; int pidx = 0;
    #pragma unroll
    for (int ii = 0; ii < 16; ++ii) {
      const int i = hi * 16 + ii;
      const float sc = al[i] + tr[i][j];
      if (sc > pmax) { pmax = sc; pidx = i; }   // strict > => first occurrence
    }
    const float omax = __shfl_down(pmax, 32);
    const int   oidx = __shfl_down(pidx, 32);
    if (l < 32) {
      if (omax > pmax) { pmax = omax; pidx = oidx; } // high half only on strict >
      bp[t][j] = (unsigned char)pidx;
      const float e = Ef[(size_t)t * (NTAGS * Bn) + j * Bn + b]
                    + Eb[(size_t)t * (NTAGS * Bn) + j * Bn + b] + bout[j];
      const float na = pmax + e;
      if (msk[t] > 0.f) al[j] = na;
    }
    __syncthreads();
  }

  float fv; int fidx;
  if (l < 32) { fv = al[l] + tr[l][31]; fidx = l; }
  else        { fv = -FLT_MAX; fidx = 1 << 30; }
  #pragma unroll
  for (int off = 16; off >= 1; off >>= 1) {
    const float v2 = __shfl_xor(fv, off);
    const int   i2 = __shfl_xor(fidx, off);
    if (v2 > fv || (v2 == fv && i2 < fidx)) { fv = v2; fidx = i2; }
  }
  if (l == 0) {
    out[b] = fv;
    int cur = fidx;
    tseq[511] = cur;
    for (int t = 511; t >= 1; --t) {
      const int prev = (msk[t] > 0.f) ? (int)bp[t][cur] : cur;
      tseq[t - 1] = prev;
      cur = prev;
    }
  }
  __syncthreads();
  for (int t = l; t < 512; t += 64) {
    const float tv = (msk[t] > 0.f) ? (float)tseq[t] : -1.0f;
    out[Bn + (size_t)b * 512 + t] = tv;
  }
}

extern "C" void kernel_launch(void* const* d_in, const int* in_sizes, int n_in,
                              void* d_out, int out_size, void* d_ws, size_t ws_size,
                              hipStream_t stream) {
  const float* X      = (const float*)d_in[0];
  const float* masks  = (const float*)d_in[1];
  const float* Wih_f  = (const float*)d_in[3];
  const float* Whh_f  = (const float*)d_in[4];
  const float* bf     = (const float*)d_in[5];
  const float* Wih_b  = (const float*)d_in[6];
  const float* Whh_b  = (const float*)d_in[7];
  const float* bb     = (const float*)d_in[8];
  const float* Wout   = (const float*)d_in[9];
  const float* bout   = (const float*)d_in[10];
  const float* trans  = (const float*)d_in[11];
  float* ws  = (float*)d_ws;
  float* out = (float*)d_out;

  // zero h/c state region (graph replays re-run this)
  hipMemsetAsync(d_ws, 0, (size_t)OFF_EF * sizeof(float), stream);

  for (int s = 0; s < Tn; ++s)
    lstm_step_k<<<256, 512, 0, stream>>>(X, masks, Wih_f, Whh_f, bf,
                                         Wih_b, Whh_b, bb, Wout, ws, s);
  emis_final_k<<<64, 512, 0, stream>>>(Wout, ws);
  viterbi_k<<<128, 64, 0, stream>>>(ws + OFF_EF, ws + OFF_EB, bout, trans, masks, out);
}

// Round 9
// 14076.482 us; speedup vs baseline: 1.0385x; 1.0385x over previous
//
#include <hip/hip_runtime.h>
#include <cfloat>
#include <cmath>

#define Bn 128
#define Tn 512
#define En 256
#define Hn 512
#define NTAGS 32

// ws float offsets (h stored [k][b] dense)
#define OFF_HF 0                          // [2][512][128]
#define OFF_HB 131072
#define OFF_CF 262144                     // [512][128]
#define OFF_CB 327680
#define OFF_EF 393216                     // [512][32][128]
#define OFF_EB 2490368
// end 4587520 floats = 17.5 MB

__global__ __launch_bounds__(512, 4) void lstm_step_k(
    const float* __restrict__ X, const float* __restrict__ masks,
    const float* __restrict__ Wih_f, const float* __restrict__ Whh_f, const float* __restrict__ bias_f,
    const float* __restrict__ Wih_b, const float* __restrict__ Whh_b, const float* __restrict__ bias_b,
    const float* __restrict__ Wout, float* __restrict__ ws, int s)
{
  __shared__ __align__(16) float P[8 * 8 * 128];  // 32 KB k-split partials [kq][n][b]
  __shared__ __align__(16) float GL[128 * 9];     // 4.6 KB gates [b][n]
  __shared__ __align__(16) float RS[8 * 128];     // 4 KB emission partials [kq][b]

  const int tid  = threadIdx.x;
  const int blk  = blockIdx.x;
  const int lane = tid & 63;
  const int kq   = __builtin_amdgcn_readfirstlane(tid >> 6);  // wave 0..7
  const int bg   = lane & 31;       // b quad [bg*4, +4)
  const int kh   = lane >> 5;       // k half-octile
  const int kloc = kq * 8 + kh * 4; // k offset within 64-chunk

  const int dir = blk >> 8;
  const int bbk = blk & 255;
  const int t = dir ? (Tn - 1 - s) : s;
  const float* Wih  = dir ? Wih_b  : Wih_f;
  const float* Whh  = dir ? Whh_b  : Whh_f;
  const float* bias = dir ? bias_b : bias_f;
  float* hbuf = ws + (dir ? OFF_HB : OFF_HF);
  float* cbuf = ws + (dir ? OFF_CB : OFF_CF);
  const float* hprev = hbuf + ((s + 1) & 1) * (Hn * Bn);
  float*       hnext = hbuf + (s & 1) * (Hn * Bn);
  const int hidx0 = bbk * 2;        // block owns h-indices {hidx0, hidx0+1} -> 8 gate cols
  const int etag  = bbk & 31;
  const int ebq   = bbk >> 5;

  // ---- epilogue preloads (issued early, consumed at end) ----
  const int pb  = tid & 127;
  const int phh = (tid >> 7) & 1;
  const int hidxp = hidx0 + phh;
  float mval = 0.f, bi = 0.f, bf_ = 0.f, bg_ = 0.f, bo_ = 0.f, cold = 0.f, hold = 0.f;
  if (tid < 256) {
    mval = masks[(size_t)pb * Tn + t];
    bi  = bias[hidxp];
    bf_ = bias[Hn + hidxp];
    bg_ = bias[2 * Hn + hidxp];
    bo_ = bias[3 * Hn + hidxp];
    cold = cbuf[hidxp * Bn + pb];
    hold = hprev[hidxp * Bn + pb];
  }

  const float* wor = Wout + (size_t)etag * (2 * Hn) + dir * Hn;

  float acc[4][8];
  #pragma unroll
  for (int m = 0; m < 4; ++m)
    #pragma unroll
    for (int n = 0; n < 8; ++n) acc[m][n] = 0.f;
  float eac[4] = {0.f, 0.f, 0.f, 0.f};

  // ---- h-part: k = 0..511, all operands straight from global/L2, no barriers ----
  #pragma unroll 1
  for (int c = 0; c < 8; ++c) {
    const int k0 = c * 64 + kloc;
    const float* ap = hprev + (size_t)k0 * Bn + bg * 4;
    const float4 A0 = *(const float4*)(ap);
    const float4 A1 = *(const float4*)(ap + Bn);
    const float4 A2 = *(const float4*)(ap + 2 * Bn);
    const float4 A3 = *(const float4*)(ap + 3 * Bn);
    float4 Wv[8];
    #pragma unroll
    for (int n = 0; n < 8; ++n) {
      const int cgl = (n >> 1) * Hn + hidx0 + (n & 1);
      Wv[n] = *(const float4*)(Whh + (size_t)cgl * Hn + k0);
    }
    const float4 wo4 = *(const float4*)(wor + k0);
    const float a0[4] = {A0.x, A0.y, A0.z, A0.w};
    const float a1[4] = {A1.x, A1.y, A1.z, A1.w};
    const float a2[4] = {A2.x, A2.y, A2.z, A2.w};
    const float a3[4] = {A3.x, A3.y, A3.z, A3.w};
    #pragma unroll
    for (int n = 0; n < 8; ++n) {
      const float w0 = Wv[n].x, w1 = Wv[n].y, w2 = Wv[n].z, w3 = Wv[n].w;
      #pragma unroll
      for (int m = 0; m < 4; ++m) {
        acc[m][n] += a0[m] * w0;
        acc[m][n] += a1[m] * w1;
        acc[m][n] += a2[m] * w2;
        acc[m][n] += a3[m] * w3;
      }
    }
    #pragma unroll
    for (int m = 0; m < 4; ++m) {
      eac[m] += a0[m] * wo4.x;
      eac[m] += a1[m] * wo4.y;
      eac[m] += a2[m] * wo4.z;
      eac[m] += a3[m] * wo4.w;
    }
  }

  // ---- x-part: e = 0..255, X float4 along e per batch row ----
  #pragma unroll 1
  for (int c = 0; c < 4; ++c) {
    const int e0 = c * 64 + kloc;
    const float* xp = X + (size_t)(bg * 4) * (Tn * En) + (size_t)t * En + e0;
    const float4 X0 = *(const float4*)(xp);
    const float4 X1 = *(const float4*)(xp + Tn * En);
    const float4 X2 = *(const float4*)(xp + 2 * (Tn * En));
    const float4 X3 = *(const float4*)(xp + 3 * (Tn * En));
    float4 Wv[8];
    #pragma unroll
    for (int n = 0; n < 8; ++n) {
      const int cgl = (n >> 1) * Hn + hidx0 + (n & 1);
      Wv[n] = *(const float4*)(Wih + (size_t)cgl * En + e0);
    }
    #pragma unroll
    for (int n = 0; n < 8; ++n) {
      const float w0 = Wv[n].x, w1 = Wv[n].y, w2 = Wv[n].z, w3 = Wv[n].w;
      acc[0][n] += X0.x * w0; acc[0][n] += X0.y * w1; acc[0][n] += X0.z * w2; acc[0][n] += X0.w * w3;
      acc[1][n] += X1.x * w0; acc[1][n] += X1.y * w1; acc[1][n] += X1.z * w2; acc[1][n] += X1.w * w3;
      acc[2][n] += X2.x * w0; acc[2][n] += X2.y * w1; acc[2][n] += X2.z * w2; acc[2][n] += X2.w * w3;
      acc[3][n] += X3.x * w0; acc[3][n] += X3.y * w1; acc[3][n] += X3.z * w2; acc[3][n] += X3.w * w3;
    }
  }

  // ---- kh-pair reduce in-register ----
  #pragma unroll
  for (int m = 0; m < 4; ++m)
    #pragma unroll
    for (int n = 0; n < 8; ++n)
      acc[m][n] += __shfl_xor(acc[m][n], 32);
  #pragma unroll
  for (int m = 0; m < 4; ++m) eac[m] += __shfl_xor(eac[m], 32);

  // ---- kq (8-way) reduction via LDS ----
  if (kh == 0) {
    #pragma unroll
    for (int n = 0; n < 8; ++n)
      *(float4*)&P[(kq * 8 + n) * 128 + bg * 4] =
          make_float4(acc[0][n], acc[1][n], acc[2][n], acc[3][n]);
    *(float4*)&RS[kq * 128 + bg * 4] = make_float4(eac[0], eac[1], eac[2], eac[3]);
  }
  __syncthreads();
  {
    const int b  = tid & 127;
    const int nq = tid >> 7;                     // 0..3
    #pragma unroll
    for (int nn = 0; nn < 2; ++nn) {
      const int n = nq * 2 + nn;
      float v = 0.f;
      #pragma unroll
      for (int k2 = 0; k2 < 8; ++k2)
        v += P[(k2 * 8 + n) * 128 + b];
      GL[b * 9 + n] = v;
    }
  }
  // emission finish (between barriers; RS complete since barrier 1)
  if (s > 0 && ebq == 0 && tid < 128) {
    const int tprev = dir ? (Tn - s) : (s - 1);
    float* Edst = ws + (dir ? OFF_EB : OFF_EF);
    float v = 0.f;
    #pragma unroll
    for (int g = 0; g < 8; ++g) v += RS[g * 128 + tid];
    Edst[(size_t)tprev * (NTAGS * Bn) + etag * Bn + tid] = v;
  }
  __syncthreads();

  // ---- LSTM pointwise update: n = gate*2 + phh ----
  if (tid < 256) {
    const float gi = GL[pb * 9 + 0 + phh] + bi;
    const float gf = GL[pb * 9 + 2 + phh] + bf_;
    const float gc = GL[pb * 9 + 4 + phh] + bg_;
    const float go = GL[pb * 9 + 6 + phh] + bo_;
    const float iv = 1.f / (1.f + expf(-gi));
    const float fv = 1.f / (1.f + expf(-gf));
    const float gv = tanhf(gc);
    const float ov = 1.f / (1.f + expf(-go));
    const float cnew = fv * cold + iv * gv;
    const float hnew = ov * tanhf(cnew);
    hnext[hidxp * Bn + pb] = (mval > 0.f) ? hnew : hold;
    cbuf[hidxp * Bn + pb]  = (mval > 0.f) ? cnew : cold;
  }
}

__global__ __launch_bounds__(512) void emis_final_k(const float* __restrict__ Wout,
                                                    float* __restrict__ ws)
{
  __shared__ float RSf[16 * Bn];
  const int tid = threadIdx.x;
  const int dir = blockIdx.x >> 5;
  const int tag = blockIdx.x & 31;
  // final states: h_f[T-1] and h_b[0] both written at s=511 (wbuf=1)
  const float* hsrc = ws + (dir ? OFF_HB : OFF_HF) + 1 * (Hn * Bn);
  const int tprev = dir ? 0 : (Tn - 1);
  const float* wrow = Wout + (size_t)tag * (2 * Hn) + dir * Hn;
  float* Edst = ws + (dir ? OFF_EB : OFF_EF);
  const int bq = tid & 31;
  const int kg = tid >> 5;
  float4 a4 = make_float4(0.f, 0.f, 0.f, 0.f);
  #pragma unroll 4
  for (int kk = 0; kk < 32; ++kk) {
    const int k = kg * 32 + kk;
    const float w = wrow[k];
    const float4 h4 = *(const float4*)&hsrc[k * Bn + bq * 4];
    a4.x += h4.x * w; a4.y += h4.y * w; a4.z += h4.z * w; a4.w += h4.w * w;
  }
  *(float4*)&RSf[kg * Bn + bq * 4] = a4;
  __syncthreads();
  if (tid < 128) {
    float v = 0.f;
    #pragma unroll
    for (int g = 0; g < 16; ++g) v += RSf[g * Bn + tid];
    Edst[(size_t)tprev * (NTAGS * Bn) + tag * Bn + tid] = v;
  }
}

__global__ __launch_bounds__(64) void viterbi_k(
    const float* __restrict__ Ef, const float* __restrict__ Eb,
    const float* __restrict__ bout, const float* __restrict__ trans,
    const float* __restrict__ masks, float* __restrict__ out)
{
  const int b = blockIdx.x;
  const int l = threadIdx.x;
  __shared__ float tr[32][32];
  __shared__ float al[32];
  __shared__ float msk[512];
  __shared__ unsigned char bp[512][32];
  __shared__ int tseq[512];

  for (int i = l; i < 1024; i += 64) tr[i >> 5][i & 31] = trans[i];
  for (int i = l; i < 512; i += 64) msk[i] = masks[(size_t)b * 512 + i];
  __syncthreads();

  const int j  = l & 31;
  const int hi = l >> 5;
  if (l < 32)
    al[j] = Ef[(size_t)j * Bn + b] + Eb[(size_t)j * Bn + b] + bout[j] + tr[30][j];
  __syncthreads();

  for (int t = 1; t < 512; ++t) {
    float pmax = -FLT_MAX; int pidx = 0;
    #pragma unroll
    for (int ii = 0; ii < 16; ++ii) {
      const int i = hi * 16 + ii;
      const float sc = al[i] + tr[i][j];
      if (sc > pmax) { pmax = sc; pidx = i; }   // strict > => first occurrence
    }
    const float omax = __shfl_down(pmax, 32);
    const int   oidx = __shfl_down(pidx, 32);
    if (l < 32) {
      if (omax > pmax) { pmax = omax; pidx = oidx; } // high half only on strict >
      bp[t][j] = (unsigned char)pidx;
      const float e = Ef[(size_t)t * (NTAGS * Bn) + j * Bn + b]
                    + Eb[(size_t)t * (NTAGS * Bn) + j * Bn + b] + bout[j];
      const float na = pmax + e;
      if (msk[t] > 0.f) al[j] = na;
    }
    __syncthreads();
  }

  float fv; int fidx;
  if (l < 32) { fv = al[l] + tr[l][31]; fidx = l; }
  else        { fv = -FLT_MAX; fidx = 1 << 30; }
  #pragma unroll
  for (int off = 16; off >= 1; off >>= 1) {
    const float v2 = __shfl_xor(fv, off);
    const int   i2 = __shfl_xor(fidx, off);
    if (v2 > fv || (v2 == fv && i2 < fidx)) { fv = v2; fidx = i2; }
  }
  if (l == 0) {
    out[b] = fv;
    int cur = fidx;
    tseq[511] = cur;
    for (int t = 511; t >= 1; --t) {
      const int prev = (msk[t] > 0.f) ? (int)bp[t][cur] : cur;
      tseq[t - 1] = prev;
      cur = prev;
    }
  }
  __syncthreads();
  for (int t = l; t < 512; t += 64) {
    const float tv = (msk[t] > 0.f) ? (float)tseq[t] : -1.0f;
    out[Bn + (size_t)b * 512 + t] = tv;
  }
}

extern "C" void kernel_launch(void* const* d_in, const int* in_sizes, int n_in,
                              void* d_out, int out_size, void* d_ws, size_t ws_size,
                              hipStream_t stream) {
  const float* X      = (const float*)d_in[0];
  const float* masks  = (const float*)d_in[1];
  const float* Wih_f  = (const float*)d_in[3];
  const float* Whh_f  = (const float*)d_in[4];
  const float* bf     = (const float*)d_in[5];
  const float* Wih_b  = (const float*)d_in[6];
  const float* Whh_b  = (const float*)d_in[7];
  const float* bb     = (const float*)d_in[8];
  const float* Wout   = (const float*)d_in[9];
  const float* bout   = (const float*)d_in[10];
  const float* trans  = (const float*)d_in[11];
  float* ws  = (float*)d_ws;
  float* out = (float*)d_out;

  // zero h/c state region (graph replays re-run this)
  hipMemsetAsync(d_ws, 0, (size_t)OFF_EF * sizeof(float), stream);

  for (int s = 0; s < Tn; ++s)
    lstm_step_k<<<512, 512, 0, stream>>>(X, masks, Wih_f, Whh_f, bf,
                                         Wih_b, Whh_b, bb, Wout, ws, s);
  emis_final_k<<<64, 512, 0, stream>>>(Wout, ws);
  viterbi_k<<<128, 64, 0, stream>>>(ws + OFF_EF, ws + OFF_EB, bout, trans, masks, out);
}